// Round 1
// baseline (218.581 us; speedup 1.0000x reference)
//
#include <hip/hip_runtime.h>

#define FEAT 32

// Scatter-add message passing:
//   out[dst[e]][f] += x[src[e]][f] * w[e]
// One thread per (edge, feature). f = tid & 31 so each 32-lane half-wave
// reads one x row coalesced (128 B) and atomically adds 32 consecutive
// floats of one out row.
__global__ void MessagePassing_40793599378092_kernel(
    const float* __restrict__ x,
    const int* __restrict__ ei,      // [2*E] flat: src at [0,E), dst at [E,2E)
    const float* __restrict__ ew,    // [E]
    float* __restrict__ out,         // [N*FEAT], pre-zeroed
    int E) {
    int tid = blockIdx.x * blockDim.x + threadIdx.x;
    int e = tid >> 5;
    if (e >= E) return;
    int f = tid & 31;

    int src = ei[e];
    int dst = ei[E + e];
    float w = ew[e];

    float v = x[(long long)src * FEAT + f] * w;
    // unsafeAtomicAdd -> hardware global_atomic_add_f32 (no CAS loop).
    unsafeAtomicAdd(&out[(long long)dst * FEAT + f], v);
}

extern "C" void kernel_launch(void* const* d_in, const int* in_sizes, int n_in,
                              void* d_out, int out_size, void* d_ws, size_t ws_size,
                              hipStream_t stream) {
    const float* x  = (const float*)d_in[0];
    const int*   ei = (const int*)d_in[1];
    const float* ew = (const float*)d_in[2];
    float* out = (float*)d_out;

    const int E = in_sizes[2];           // 2,000,000 edge weights
    // d_out is poisoned (0xAA) before timing and not re-poisoned between
    // replays; atomics need a zeroed accumulator every call.
    hipMemsetAsync(d_out, 0, (size_t)out_size * sizeof(float), stream);

    const long long total = (long long)E * FEAT;   // 64M threads
    const int block = 256;
    const int grid = (int)((total + block - 1) / block);
    MessagePassing_40793599378092_kernel<<<grid, block, 0, stream>>>(x, ei, ew, out, E);
}